// Round 8
// baseline (112.789 us; speedup 1.0000x reference)
//
#include <hip/hip_runtime.h>
#include <hip/hip_bf16.h>
#include <math.h>

// Problem constants
#define BB 32
#define TT 4096
#define CC 64
#define DD 512
#define NW 31          // number of windows
#define WIN 256
#define HOP 128
#define NROWS (BB * NW)   // 992

typedef float f32x4 __attribute__((ext_vector_type(4)));

// ---------------------------------------------------------------------------
// Kernel 1: band power via folded Goertzel. (unchanged from round 4)
// ---------------------------------------------------------------------------
__global__ __launch_bounds__(512) void k_bandpower(const float* __restrict__ x,
                                                   float* __restrict__ feat) {
    __shared__ float lds[16384];         // 64 KB
    float* u = lds;                      // [128][64]
    float* v = lds + 8192;               // [128][64]

    const int tid = threadIdx.x;
    const int c   = tid & 63;
    const int g   = tid >> 6;            // wave id 0..7
    const int blk = blockIdx.x;          // 0..991
    const int b   = blk / NW;
    const int n   = blk % NW;

    // staged fold: read both halves once, write u,v (coalesced f32x4)
    const size_t winBase = ((size_t)b * TT + (size_t)n * HOP) * CC;
    const f32x4* h0 = (const f32x4*)(x + winBase);              // t = 0..127
    const f32x4* h1 = (const f32x4*)(x + winBase + 128 * CC);   // t = 128..255
    f32x4* u4 = (f32x4*)u;
    f32x4* v4 = (f32x4*)v;
    for (int i = tid; i < 2048; i += 512) {
        const f32x4 a  = h0[i];
        const f32x4 bb = h1[i];
        u4[i] = a + bb;
        v4[i] = a - bb;
    }
    __syncthreads();

    // 7 Goertzel chains per thread, 128 steps, on u (even f) or v (odd f)
    float coef[7], s1[7], s2[7];
#pragma unroll
    for (int j = 0; j < 7; ++j) {
        const int f = 1 + g + 8 * j;
        coef[j] = 2.0f * cospif((float)f * (1.0f / 128.0f)); // 2cos(2pi f/256)
        s1[j] = 0.0f;
        s2[j] = 0.0f;
    }
    // parity(f) = parity(1+g): g odd -> f even -> u; g even -> f odd -> v
    const float* src = ((g & 1) ? u : v) + c;

#pragma unroll 4
    for (int tt = 0; tt < 128; ++tt) {
        const float xv = src[tt * 64];
#pragma unroll
        for (int j = 0; j < 7; ++j) {
            const float sn = fmaf(coef[j], s1[j], xv - s2[j]);
            s2[j] = s1[j];
            s1[j] = sn;
        }
    }
    __syncthreads();   // done reading u/v; lds is re-aliased below

    // per-thread band sums
    float pb[5] = {0.0f, 0.0f, 0.0f, 0.0f, 0.0f};
#pragma unroll
    for (int j = 0; j < 7; ++j) {
        const int f = 1 + g + 8 * j;
        if (f > 50) continue;            // wave-uniform guard
        const float p = fmaf(s1[j], s1[j],
                        fmaf(s2[j], s2[j], -coef[j] * s1[j] * s2[j]));
        if (f <= 4)             pb[0] += p;
        if (f >= 4 && f <= 8)   pb[1] += p;
        if (f >= 8 && f <= 13)  pb[2] += p;
        if (f >= 13 && f <= 30) pb[3] += p;
        if (f >= 30)            pb[4] += p;
    }

    // cross-wave reduction via re-aliased LDS (each (g,k,c) written once)
    float (*bpart)[5][64] = (float (*)[5][64])lds;
#pragma unroll
    for (int k = 0; k < 5; ++k) bpart[g][k][c] = pb[k];
    __syncthreads();

    const float wband[5] = {1.0f / 4.0f, 1.0f / 5.0f, 1.0f / 6.0f,
                            1.0f / 18.0f, 1.0f / 21.0f};
    for (int idx = tid; idx < 320; idx += 512) {
        const int k  = idx >> 6;
        const int cc = idx & 63;
        float s = 0.0f;
#pragma unroll
        for (int gg = 0; gg < 8; ++gg) s += bpart[gg][k][cc];
        feat[(size_t)blk * 320 + idx] = s * wband[k];
    }
}

// ---------------------------------------------------------------------------
// Kernel 2: MLP. 8 rows per block, 256 threads. (round-4 version --
// amortizes the 832 KB W1+W2 read over 8 rows; 124 blocks total)
// ---------------------------------------------------------------------------
__global__ __launch_bounds__(256) void k_mlp(const float* __restrict__ feat,
                                             const float* __restrict__ W1,
                                             const float* __restrict__ b1,
                                             const float* __restrict__ W2,
                                             const float* __restrict__ b2,
                                             float* __restrict__ feat2) {
    __shared__ float fs[8][320];
    __shared__ float hs[8][256];

    const int tid  = threadIdx.x;
    const int row0 = blockIdx.x * 8;

    for (int i = tid; i < 8 * 320; i += 256)
        ((float*)fs)[i] = feat[(size_t)row0 * 320 + i];
    __syncthreads();

    // phase 1: hidden (256 wide), thread owns column tid
    float acc[8];
    {
        const float bias = b1[tid];
#pragma unroll
        for (int r = 0; r < 8; ++r) acc[r] = bias;
        for (int i = 0; i < 320; ++i) {
            const float w = W1[(size_t)i * 256 + tid];
#pragma unroll
            for (int r = 0; r < 8; ++r) acc[r] = fmaf(fs[r][i], w, acc[r]);
        }
#pragma unroll
        for (int r = 0; r < 8; ++r) hs[r][tid] = fmaxf(acc[r], 0.0f);
    }
    __syncthreads();

    // phase 2: output (512 wide), thread owns columns tid and tid+256
    float o0[8], o1[8];
    {
        const float bias0 = b2[tid];
        const float bias1 = b2[tid + 256];
#pragma unroll
        for (int r = 0; r < 8; ++r) { o0[r] = bias0; o1[r] = bias1; }
        for (int i = 0; i < 256; ++i) {
            const float w0 = W2[(size_t)i * 512 + tid];
            const float w1 = W2[(size_t)i * 512 + tid + 256];
#pragma unroll
            for (int r = 0; r < 8; ++r) {
                const float h = hs[r][i];
                o0[r] = fmaf(h, w0, o0[r]);
                o1[r] = fmaf(h, w1, o1[r]);
            }
        }
    }
#pragma unroll
    for (int r = 0; r < 8; ++r) {
        feat2[(size_t)(row0 + r) * 512 + tid]       = o0[r];
        feat2[(size_t)(row0 + r) * 512 + tid + 256] = o1[r];
    }
}

// ---------------------------------------------------------------------------
// Kernel 3: span-streaming interp. One block per (b, i0-span, half-span):
// 992 spans x 2 = 1984 blocks (7.75/CU). Block loads its two feat2 rows
// (4 KB, L2-hot) into REGISTERS, then runs a load-free store loop over its
// ~66 t's (132 KB contiguous). Same i0(pos) predicate as the per-t formula
// -> every t written exactly once with the exact reference weights.
// ---------------------------------------------------------------------------
__device__ __forceinline__ int i0_of(int t) {
    float pos = ((float)t + 0.5f) * (31.0f / 4096.0f) - 0.5f;
    pos = fminf(fmaxf(pos, 0.0f), 30.0f);
    return (int)pos;
}

__device__ __forceinline__ int span_start(int i) {
    if (i <= 0) return 0;
    if (i >= 31) return TT;
    int t = (int)(((float)i + 0.5f) * (4096.0f / 31.0f) - 0.5f) - 4;
    if (t < 0) t = 0;
    // first t with i0_of(t) >= i (monotone; guess is ~4 below the crossing)
    while (t < TT && i0_of(t) < i) ++t;
    return t;
}

__global__ __launch_bounds__(256) void k_interp_span(const float* __restrict__ feat2,
                                                     float* __restrict__ out) {
    const int tid  = threadIdx.x;
    const int blk  = blockIdx.x;         // 0..1983
    const int sub  = blk & 1;            // half-span selector
    const int sp   = blk >> 1;           // 0..991
    const int b    = sp / NW;
    const int i    = sp % NW;
    const int r1   = min(i + 1, NW - 1);
    const int d4   = tid & 127;          // f32x4 slot within the 512-row
    const int half = tid >> 7;           // 0/1: even/odd t

    const f32x4 va = ((const f32x4*)(feat2 + ((size_t)b * NW + i)  * DD))[d4];
    const f32x4 vb = ((const f32x4*)(feat2 + ((size_t)b * NW + r1) * DD))[d4];
    const f32x4 vd = vb - va;

    const int tS  = span_start(i);
    const int tE  = span_start(i + 1);
    const int mid = tS + ((tE - tS) >> 1);
    const int t0  = sub ? mid : tS;
    const int t1  = sub ? tE  : mid;

    for (int t = t0 + half; t < t1; t += 2) {
        float pos = ((float)t + 0.5f) * (31.0f / 4096.0f) - 0.5f;
        pos = fminf(fmaxf(pos, 0.0f), 30.0f);
        const float w = pos - (float)i;
        const f32x4 res = va + w * vd;
        f32x4* o = (f32x4*)(out + ((size_t)b * TT + t) * DD);
        o[d4] = res;
    }
}

// ---------------------------------------------------------------------------
extern "C" void kernel_launch(void* const* d_in, const int* in_sizes, int n_in,
                              void* d_out, int out_size, void* d_ws, size_t ws_size,
                              hipStream_t stream) {
    const float* x  = (const float*)d_in[0];
    const float* W1 = (const float*)d_in[1];
    const float* b1 = (const float*)d_in[2];
    const float* W2 = (const float*)d_in[3];
    const float* b2 = (const float*)d_in[4];
    float* out = (float*)d_out;

    float* feat  = (float*)d_ws;                 // NROWS*320 floats = 1.27 MB
    float* feat2 = feat + (size_t)NROWS * 320;   // NROWS*512 floats = 2.03 MB

    k_bandpower<<<NROWS, 512, 0, stream>>>(x, feat);
    k_mlp<<<NROWS / 8, 256, 0, stream>>>(feat, W1, b1, W2, b2, feat2);
    k_interp_span<<<NROWS * 2, 256, 0, stream>>>(feat2, out);
}

// Round 9
// 100.164 us; speedup vs baseline: 1.1260x; 1.1260x over previous
//
#include <hip/hip_runtime.h>
#include <hip/hip_bf16.h>
#include <math.h>

// Problem constants
#define BB 32
#define TT 4096
#define CC 64
#define DD 512
#define NW 31          // number of windows
#define WIN 256
#define HOP 128
#define NROWS (BB * NW)   // 992

typedef float f32x4 __attribute__((ext_vector_type(4)));

// ---------------------------------------------------------------------------
// Kernel 1: band power via folded Goertzel. (unchanged from round 4)
// ---------------------------------------------------------------------------
__global__ __launch_bounds__(512) void k_bandpower(const float* __restrict__ x,
                                                   float* __restrict__ feat) {
    __shared__ float lds[16384];         // 64 KB
    float* u = lds;                      // [128][64]
    float* v = lds + 8192;               // [128][64]

    const int tid = threadIdx.x;
    const int c   = tid & 63;
    const int g   = tid >> 6;            // wave id 0..7
    const int blk = blockIdx.x;          // 0..991
    const int b   = blk / NW;
    const int n   = blk % NW;

    // staged fold: read both halves once, write u,v (coalesced f32x4)
    const size_t winBase = ((size_t)b * TT + (size_t)n * HOP) * CC;
    const f32x4* h0 = (const f32x4*)(x + winBase);              // t = 0..127
    const f32x4* h1 = (const f32x4*)(x + winBase + 128 * CC);   // t = 128..255
    f32x4* u4 = (f32x4*)u;
    f32x4* v4 = (f32x4*)v;
    for (int i = tid; i < 2048; i += 512) {
        const f32x4 a  = h0[i];
        const f32x4 bb = h1[i];
        u4[i] = a + bb;
        v4[i] = a - bb;
    }
    __syncthreads();

    // 7 Goertzel chains per thread, 128 steps, on u (even f) or v (odd f)
    float coef[7], s1[7], s2[7];
#pragma unroll
    for (int j = 0; j < 7; ++j) {
        const int f = 1 + g + 8 * j;
        coef[j] = 2.0f * cospif((float)f * (1.0f / 128.0f)); // 2cos(2pi f/256)
        s1[j] = 0.0f;
        s2[j] = 0.0f;
    }
    // parity(f) = parity(1+g): g odd -> f even -> u; g even -> f odd -> v
    const float* src = ((g & 1) ? u : v) + c;

#pragma unroll 4
    for (int tt = 0; tt < 128; ++tt) {
        const float xv = src[tt * 64];
#pragma unroll
        for (int j = 0; j < 7; ++j) {
            const float sn = fmaf(coef[j], s1[j], xv - s2[j]);
            s2[j] = s1[j];
            s1[j] = sn;
        }
    }
    __syncthreads();   // done reading u/v; lds is re-aliased below

    // per-thread band sums
    float pb[5] = {0.0f, 0.0f, 0.0f, 0.0f, 0.0f};
#pragma unroll
    for (int j = 0; j < 7; ++j) {
        const int f = 1 + g + 8 * j;
        if (f > 50) continue;            // wave-uniform guard
        const float p = fmaf(s1[j], s1[j],
                        fmaf(s2[j], s2[j], -coef[j] * s1[j] * s2[j]));
        if (f <= 4)             pb[0] += p;
        if (f >= 4 && f <= 8)   pb[1] += p;
        if (f >= 8 && f <= 13)  pb[2] += p;
        if (f >= 13 && f <= 30) pb[3] += p;
        if (f >= 30)            pb[4] += p;
    }

    // cross-wave reduction via re-aliased LDS (each (g,k,c) written once)
    float (*bpart)[5][64] = (float (*)[5][64])lds;
#pragma unroll
    for (int k = 0; k < 5; ++k) bpart[g][k][c] = pb[k];
    __syncthreads();

    const float wband[5] = {1.0f / 4.0f, 1.0f / 5.0f, 1.0f / 6.0f,
                            1.0f / 18.0f, 1.0f / 21.0f};
    for (int idx = tid; idx < 320; idx += 512) {
        const int k  = idx >> 6;
        const int cc = idx & 63;
        float s = 0.0f;
#pragma unroll
        for (int gg = 0; gg < 8; ++gg) s += bpart[gg][k][cc];
        feat[(size_t)blk * 320 + idx] = s * wband[k];
    }
}

// ---------------------------------------------------------------------------
// Fused MLP + interp, v2 (de-duplicated).
// One block per (b, span-pair): 512 blocks = 2/CU. Block grp<15 owns spans
// {2g, 2g+1} and computes MLP rows {2g, 2g+1, 2g+2} ONCE (vs round 7's
// per-span recompute: 3x less row work, 1.9x less weight traffic than 992
// blocks). grp==15 owns span 30 (rows clamp to 30). Then the round-7
// winning store loop: per span, va/vd from LDS, pure contiguous f32x4
// stores (~132 rows/span), zero loads at store time.
// ---------------------------------------------------------------------------
__device__ __forceinline__ int i0_of(int t) {
    float pos = ((float)t + 0.5f) * (31.0f / 4096.0f) - 0.5f;
    pos = fminf(fmaxf(pos, 0.0f), 30.0f);
    return (int)pos;
}

__device__ __forceinline__ int span_start(int i) {
    if (i <= 0) return 0;
    if (i >= 31) return TT;
    int t = (int)(((float)i + 0.5f) * (4096.0f / 31.0f) - 0.5f) - 4;
    if (t < 0) t = 0;
    // first t with i0_of(t) >= i (monotone; guess is ~4 below the crossing)
    while (t < TT && i0_of(t) < i) ++t;
    return t;
}

__global__ __launch_bounds__(256) void k_mlp_interp2(const float* __restrict__ feat,
                                                     const float* __restrict__ W1,
                                                     const float* __restrict__ b1,
                                                     const float* __restrict__ W2,
                                                     const float* __restrict__ b2,
                                                     float* __restrict__ out) {
    __shared__ float fs[3][320];
    __shared__ float hs[3][256];
    __shared__ float ABs[3][512];

    const int tid  = threadIdx.x;
    const int blk  = blockIdx.x;         // 0..511
    const int b    = blk >> 4;           // batch
    const int grp  = blk & 15;           // span-pair group
    const int i0s  = grp * 2;            // first span of this block
    const int nSp  = (grp == 15) ? 1 : 2;
    const int r0   = i0s;                // first MLP row

    // stage the (up to) 3 feat rows, row index clamped to 30
#pragma unroll
    for (int r = 0; r < 3; ++r) {
        const int rr = min(r0 + r, NW - 1);
        const float* fr = feat + ((size_t)b * NW + rr) * 320;
        for (int k = tid; k < 320; k += 256) fs[r][k] = fr[k];
    }
    __syncthreads();

    // MLP phase 1: hidden (256), thread owns column tid, 3 rows
    {
        const float bias = b1[tid];
        float a0 = bias, a1 = bias, a2 = bias;
        for (int k = 0; k < 320; ++k) {
            const float w = W1[(size_t)k * 256 + tid];
            a0 = fmaf(fs[0][k], w, a0);
            a1 = fmaf(fs[1][k], w, a1);
            a2 = fmaf(fs[2][k], w, a2);
        }
        hs[0][tid] = fmaxf(a0, 0.0f);
        hs[1][tid] = fmaxf(a1, 0.0f);
        hs[2][tid] = fmaxf(a2, 0.0f);
    }
    __syncthreads();

    // MLP phase 2: output (512), thread owns columns tid and tid+256, 3 rows
    {
        const float bias0 = b2[tid];
        const float bias1 = b2[tid + 256];
        float o00 = bias0, o10 = bias0, o20 = bias0;
        float o01 = bias1, o11 = bias1, o21 = bias1;
        for (int k = 0; k < 256; ++k) {
            const float w0 = W2[(size_t)k * 512 + tid];
            const float w1 = W2[(size_t)k * 512 + tid + 256];
            const float h0 = hs[0][k];
            const float h1 = hs[1][k];
            const float h2 = hs[2][k];
            o00 = fmaf(h0, w0, o00);
            o01 = fmaf(h0, w1, o01);
            o10 = fmaf(h1, w0, o10);
            o11 = fmaf(h1, w1, o11);
            o20 = fmaf(h2, w0, o20);
            o21 = fmaf(h2, w1, o21);
        }
        ABs[0][tid] = o00; ABs[0][tid + 256] = o01;
        ABs[1][tid] = o10; ABs[1][tid + 256] = o11;
        ABs[2][tid] = o20; ABs[2][tid + 256] = o21;
    }
    __syncthreads();

    // store stream: per span, res(t) = A + w(t)*(B-A); pure contiguous stores
    const int d4   = tid & 127;          // f32x4 slot within the 512-row
    const int half = tid >> 7;           // 0/1: even/odd t

    for (int s = 0; s < nSp; ++s) {
        const int i     = i0s + s;
        const int r1idx = min(i + 1, NW - 1) - r0;   // s+1, or 0 for span 30
        const f32x4 va  = ((const f32x4*)ABs[s])[d4];
        const f32x4 vd  = ((const f32x4*)ABs[r1idx])[d4] - va;

        const int tS = span_start(i);
        const int tE = span_start(i + 1);
        for (int t = tS + half; t < tE; t += 2) {
            float pos = ((float)t + 0.5f) * (31.0f / 4096.0f) - 0.5f;
            pos = fminf(fmaxf(pos, 0.0f), 30.0f);
            const float w = pos - (float)i;
            const f32x4 res = va + w * vd;
            f32x4* o = (f32x4*)(out + ((size_t)b * TT + t) * DD);
            o[d4] = res;
        }
    }
}

// ---------------------------------------------------------------------------
extern "C" void kernel_launch(void* const* d_in, const int* in_sizes, int n_in,
                              void* d_out, int out_size, void* d_ws, size_t ws_size,
                              hipStream_t stream) {
    const float* x  = (const float*)d_in[0];
    const float* W1 = (const float*)d_in[1];
    const float* b1 = (const float*)d_in[2];
    const float* W2 = (const float*)d_in[3];
    const float* b2 = (const float*)d_in[4];
    float* out = (float*)d_out;

    float* feat = (float*)d_ws;                  // NROWS*320 floats = 1.27 MB

    k_bandpower<<<NROWS, 512, 0, stream>>>(x, feat);
    k_mlp_interp2<<<BB * 16, 256, 0, stream>>>(feat, W1, b1, W2, b2, out);
}